// Round 1
// baseline (54678.925 us; speedup 1.0000x reference)
//
#include <hip/hip_runtime.h>

// LSTM: B=1024, T=256, H=256, C_CLS=10, all fp32.
// Persistent-RNN design: one block per 4 batch rows (256 blocks = 256 CUs),
// 1024 threads = 16 waves. Recurrent weights (1 MB) pinned in VGPRs:
// thread (j = tid&255, q = tid>>8) holds W_*h[(64q+kk)*256 + j] for kk=0..63,
// i.e. column j, k-slice q, all 4 gates -> 256 VGPRs of weights.
// Per step: phase A = partial dot products (h broadcast from LDS),
// phase B = 4-way k-slice reduction via LDS + activations + c/h update.
// c[row q][col j] lives in a register of thread (j,q). 2 barriers/step.

#define TSTEPS 256
#define HDIM   256
#define CCLS   10
#define ROWS   4
#define KS     64
#define NG     4

__device__ __forceinline__ float sigmoid_f(float v) {
    // stable logistic: exp of negative magnitude only
    const float e = expf(-fabsf(v));
    const float d = 1.0f + e;
    const float num = (v >= 0.0f) ? 1.0f : e;
    return num / d;
}

extern "C" __global__ void __launch_bounds__(1024, 1)
lstm_persistent(const float* __restrict__ x,
                const float* __restrict__ W_gx, const float* __restrict__ W_gh, const float* __restrict__ b_g,
                const float* __restrict__ W_ix, const float* __restrict__ W_ih, const float* __restrict__ b_i,
                const float* __restrict__ W_fx, const float* __restrict__ W_fh, const float* __restrict__ b_f,
                const float* __restrict__ W_ox, const float* __restrict__ W_oh, const float* __restrict__ b_o,
                const float* __restrict__ W_ph, const float* __restrict__ b_p,
                float* __restrict__ out)
{
    __shared__ float h_s[ROWS][HDIM];                 // 4 KB
    __shared__ float x_s[ROWS][TSTEPS];               // 4 KB
    __shared__ float part[4][ROWS - 1][NG][HDIM];     // 48 KB: writer q stores row r!=q at m=r-(r>q)

    const int tid = threadIdx.x;
    const int j   = tid & (HDIM - 1);
    const int q   = tid >> 8;                         // k-slice owner, also the row this thread finishes
    const int r0  = blockIdx.x * ROWS;

    // stage this block's x rows; zero-init h
    x_s[q][j] = x[(r0 + q) * TSTEPS + j];
    h_s[q][j] = 0.0f;

    // pin recurrent weights in registers: w[g][kk] = W_?h[(q*KS+kk)*HDIM + j]
    const float* __restrict__ Wh[NG] = {W_gh, W_ih, W_fh, W_oh};
    float w[NG][KS];
    #pragma unroll
    for (int g = 0; g < NG; ++g) {
        const float* __restrict__ src = Wh[g] + (size_t)(q * KS) * HDIM + j;
        #pragma unroll
        for (int kk = 0; kk < KS; ++kk)
            w[g][kk] = src[(size_t)kk * HDIM];
    }

    // per-column input weights / biases.
    // NOTE: the reference swaps biases: f-gate uses b_o, o-gate uses b_f. Reproduced.
    float wx[NG], bb[NG];
    wx[0] = W_gx[j]; wx[1] = W_ix[j]; wx[2] = W_fx[j]; wx[3] = W_ox[j];
    bb[0] = b_g[j];  bb[1] = b_i[j];  bb[2] = b_o[j];  bb[3] = b_f[j];
    float c_reg = 0.0f;                               // c[row q][col j]

    __syncthreads();

    for (int t = 0; t < TSTEPS; ++t) {
        // ---------------- phase A: partial matvecs over own k-slice ----------------
        float acc[ROWS][NG];
        #pragma unroll
        for (int r = 0; r < ROWS; ++r)
            #pragma unroll
            for (int g = 0; g < NG; ++g) acc[r][g] = 0.0f;

        #pragma unroll
        for (int k4 = 0; k4 < KS / 4; ++k4) {
            #pragma unroll
            for (int r = 0; r < ROWS; ++r) {
                const float4 hv = *reinterpret_cast<const float4*>(&h_s[r][q * KS + k4 * 4]);
                #pragma unroll
                for (int g = 0; g < NG; ++g) {
                    acc[r][g] = fmaf(hv.x, w[g][k4 * 4 + 0], acc[r][g]);
                    acc[r][g] = fmaf(hv.y, w[g][k4 * 4 + 1], acc[r][g]);
                    acc[r][g] = fmaf(hv.z, w[g][k4 * 4 + 2], acc[r][g]);
                    acc[r][g] = fmaf(hv.w, w[g][k4 * 4 + 3], acc[r][g]);
                }
            }
        }

        // publish partials for the 3 rows this thread does NOT finish
        #pragma unroll
        for (int r = 0; r < ROWS; ++r) {
            if (r != q) {                              // wave-uniform predicate, static r
                const int m = r - (r > q ? 1 : 0);
                #pragma unroll
                for (int g = 0; g < NG; ++g)
                    part[q][m][g][j] = acc[r][g];
            }
        }
        __syncthreads();

        // ---------------- phase B: reduce + activate + state update ----------------
        // own partial for row q (static-index select, q is wave-uniform)
        float own[NG];
        #pragma unroll
        for (int r = 0; r < ROWS; ++r) {
            if (r == q) {
                #pragma unroll
                for (int g = 0; g < NG; ++g) own[g] = acc[r][g];
            }
        }
        #pragma unroll
        for (int qp = 0; qp < 4; ++qp) {
            if (qp != q) {
                const int m = q - (q > qp ? 1 : 0);
                #pragma unroll
                for (int g = 0; g < NG; ++g)
                    own[g] += part[qp][m][g][j];
            }
        }

        const float xt = x_s[q][t];
        float pre[NG];
        #pragma unroll
        for (int g = 0; g < NG; ++g)
            pre[g] = own[g] + fmaf(xt, wx[g], bb[g]);

        const float gg = tanhf(pre[0]);
        const float ii = sigmoid_f(pre[1]);
        const float ff = sigmoid_f(pre[2]);
        const float oo = sigmoid_f(pre[3]);
        c_reg = fmaf(gg, ii, c_reg * ff);
        h_s[q][j] = tanhf(c_reg) * oo;

        __syncthreads();
    }

    // ---------------- classifier head: out = h_T @ W_ph + b_p ----------------
    if (tid < ROWS * CCLS) {
        const int r  = tid / CCLS;
        const int cc = tid % CCLS;
        float acc2 = b_p[cc];
        for (int jj = 0; jj < HDIM; ++jj)
            acc2 = fmaf(h_s[r][jj], W_ph[jj * CCLS + cc], acc2);
        out[(r0 + r) * CCLS + cc] = acc2;
    }
}

extern "C" void kernel_launch(void* const* d_in, const int* in_sizes, int n_in,
                              void* d_out, int out_size, void* d_ws, size_t ws_size,
                              hipStream_t stream) {
    const float* x    = (const float*)d_in[0];
    const float* W_gx = (const float*)d_in[1];
    const float* W_gh = (const float*)d_in[2];
    const float* b_g  = (const float*)d_in[3];
    const float* W_ix = (const float*)d_in[4];
    const float* W_ih = (const float*)d_in[5];
    const float* b_i  = (const float*)d_in[6];
    const float* W_fx = (const float*)d_in[7];
    const float* W_fh = (const float*)d_in[8];
    const float* b_f  = (const float*)d_in[9];
    const float* W_ox = (const float*)d_in[10];
    const float* W_oh = (const float*)d_in[11];
    const float* b_o  = (const float*)d_in[12];
    const float* W_ph = (const float*)d_in[13];
    const float* b_p  = (const float*)d_in[14];
    float* out = (float*)d_out;

    const int B = in_sizes[0] / TSTEPS;   // 1024
    const int grid = B / ROWS;            // 256 blocks -> 1 per CU

    lstm_persistent<<<dim3(grid), dim3(1024), 0, stream>>>(
        x, W_gx, W_gh, b_g, W_ix, W_ih, b_i, W_fx, W_fh, b_f,
        W_ox, W_oh, b_o, W_ph, b_p, out);
}

// Round 2
// 12587.523 us; speedup vs baseline: 4.3439x; 4.3439x over previous
//
#include <hip/hip_runtime.h>

// LSTM B=1024, T=256, H=256, fp32. Whole-GPU persistent design:
// per step t: gates = h_t @ W (4 gates, 1024 gatecols), h_{t+1} from c-update.
// Grid = 512 blocks = 32 rowgroups (32 batch rows each) x 16 colgroups (16 hcols).
// Block = 256 thr = 64 lanes (4 gates x 16 hcols) x 4 waves (k-slices of 64).
// Weights: 64 floats/thread pinned as 32 f32x2 VGPRs (v_pk_fma_f32 path).
// h double-buffered in d_ws; per-rowgroup 16-block barrier per step (the only
// cross-block dependency is within a rowgroup). blockIdx mapping R = bid&31
// puts a rowgroup's 16 blocks on one XCD (bid%8 == R%8) for L2-local exchange;
// fences remain agent-scope so correctness does not depend on that mapping.

#define Bsz   1024
#define Tt    256
#define Hh    256
#define NCLS  10
#define RGR   32            // rows per rowgroup
#define NRG   (Bsz / RGR)   // 32 rowgroups
#define NCG   16            // colgroups
#define NTHR  256

typedef __attribute__((ext_vector_type(2))) float f32x2;

__device__ __forceinline__ float sigmoid_f(float v) {
    const float e = expf(-fabsf(v));
    const float d = 1.0f + e;
    const float num = (v >= 0.0f) ? 1.0f : e;
    return num / d;
}

// 16-block sense-reversing barrier; b[0]=arrive ctr, b[1]=generation.
// memsetAsync zeroes the region before each kernel call.
__device__ __forceinline__ void rg_barrier(unsigned* b) {
    __syncthreads();
    if (threadIdx.x == 0) {
        unsigned gen = __hip_atomic_load(b + 1, __ATOMIC_RELAXED, __HIP_MEMORY_SCOPE_AGENT);
        __builtin_amdgcn_fence(__ATOMIC_RELEASE, "agent");   // flush our h stores (cache-wide)
        unsigned pos = __hip_atomic_fetch_add(b, 1u, __ATOMIC_RELAXED, __HIP_MEMORY_SCOPE_AGENT);
        if (pos == 16u - 1u) {
            __hip_atomic_store(b, 0u, __ATOMIC_RELAXED, __HIP_MEMORY_SCOPE_AGENT);
            __hip_atomic_store(b + 1, gen + 1u, __ATOMIC_RELEASE, __HIP_MEMORY_SCOPE_AGENT);
        } else {
            while (__hip_atomic_load(b + 1, __ATOMIC_RELAXED, __HIP_MEMORY_SCOPE_AGENT) == gen)
                __builtin_amdgcn_s_sleep(2);
        }
    }
    __syncthreads();
    __builtin_amdgcn_fence(__ATOMIC_ACQUIRE, "agent");       // invalidate stale h lines
}

extern "C" __global__ void __launch_bounds__(NTHR, 2)
lstm_rg(const float* __restrict__ x,
        const float* __restrict__ W_gx, const float* __restrict__ W_gh, const float* __restrict__ b_g,
        const float* __restrict__ W_ix, const float* __restrict__ W_ih, const float* __restrict__ b_i,
        const float* __restrict__ W_fx, const float* __restrict__ W_fh, const float* __restrict__ b_f,
        const float* __restrict__ W_ox, const float* __restrict__ W_oh, const float* __restrict__ b_o,
        const float* __restrict__ W_ph, const float* __restrict__ b_p,
        float* __restrict__ out, float* __restrict__ hbuf, unsigned* __restrict__ bar)
{
    __shared__ float part[4][RGR][64];   // 32 KB k-slice partials

    const int tid  = threadIdx.x;
    const int lane = tid & 63;
    const int q    = tid >> 6;           // wave = k-slice [q*64, q*64+64)
    const int g    = lane >> 4;          // gate 0:g 1:i 2:f 3:o
    const int hc   = lane & 15;
    const int R    = blockIdx.x & 31;    // rowgroup (XCD-local: bid%8 == R%8)
    const int Cg   = blockIdx.x >> 5;    // colgroup
    const int r0   = R * RGR;
    const int j    = Cg * 16 + hc;       // global h-column

    // --- pin this thread's 64 recurrent weights as 32 f32x2 regs ---
    const float* __restrict__ Wh =
        (g == 0) ? W_gh : (g == 1) ? W_ih : (g == 2) ? W_fh : W_oh;
    const float* __restrict__ wsrc = Wh + (size_t)(q * 64) * Hh + j;
    f32x2 w2[32];
    #pragma unroll
    for (int p = 0; p < 32; ++p) {
        f32x2 t2;
        t2.x = wsrc[(size_t)(2 * p) * Hh];
        t2.y = wsrc[(size_t)(2 * p + 1) * Hh];
        w2[p] = t2;
    }

    // per-column input weight + bias. Reference swap preserved:
    // f-gate (g==2) uses b_o, o-gate (g==3) uses b_f.
    const float wxv = ((g == 0) ? W_gx : (g == 1) ? W_ix : (g == 2) ? W_fx : W_ox)[j];
    const float bbv = ((g == 0) ? b_g  : (g == 1) ? b_i  : (g == 2) ? b_o  : b_f )[j];

    float c[8];
    #pragma unroll
    for (int rr = 0; rr < 8; ++rr) c[rr] = 0.0f;

    unsigned* myBar = bar + (size_t)R * 16;

    for (int t = 0; t < Tt; ++t) {
        const float* __restrict__ hcur = hbuf + ((t & 1) ? (size_t)(Bsz * Hh) : (size_t)0);
        float*       __restrict__ hnxt = hbuf + ((t & 1) ? (size_t)0 : (size_t)(Bsz * Hh));

        // prefetch x_t for the 8 rows this wave finishes (used in phase B)
        float xts[8];
        #pragma unroll
        for (int rr = 0; rr < 8; ++rr)
            xts[rr] = x[(size_t)(r0 + q * 8 + rr) * Tt + t];

        // ---------- phase A: partial matvecs, all 32 rows, own k-slice ----------
        const float* hbase = hcur + (size_t)r0 * Hh + q * 64;
        asm volatile("" : "+v"(hbase));   // keep pointer in VGPRs -> vector loads (no scalar-cache path)

        f32x2 acc[RGR];
        #pragma unroll
        for (int r = 0; r < RGR; ++r) { acc[r].x = 0.0f; acc[r].y = 0.0f; }

        #pragma unroll
        for (int r = 0; r < RGR; ++r) {
            const float4* hp4 = reinterpret_cast<const float4*>(hbase + (size_t)r * Hh);
            #pragma unroll
            for (int p4 = 0; p4 < 16; ++p4) {
                const float4 hv = hp4[p4];
                f32x2 a; a.x = hv.x; a.y = hv.y;
                f32x2 b; b.x = hv.z; b.y = hv.w;
                acc[r] = __builtin_elementwise_fma(a, w2[2 * p4],     acc[r]);
                acc[r] = __builtin_elementwise_fma(b, w2[2 * p4 + 1], acc[r]);
            }
        }

        #pragma unroll
        for (int r = 0; r < RGR; ++r)
            part[q][r][lane] = acc[r].x + acc[r].y;
        __syncthreads();

        // ---------- phase B: reduce k-slices, activate, update c/h ----------
        #pragma unroll
        for (int rr = 0; rr < 8; ++rr) {
            const int row = q * 8 + rr;
            float s = part[0][row][lane] + part[1][row][lane]
                    + part[2][row][lane] + part[3][row][lane];
            float pre = s + fmaf(xts[rr], wxv, bbv);
            float act = (g == 0) ? tanhf(pre) : sigmoid_f(pre);
            float y1 = __shfl_xor(act, 16);
            float y2 = __shfl_xor(act, 32);
            float y3 = __shfl_xor(y1, 32);
            // value of gate G sits in: act (g==G), y1 (g==G^1), y2 (g==G^2), y3 (g==G^3)
            float gg = (g == 0) ? act : (g == 1) ? y1 : (g == 2) ? y2 : y3;
            float ii = (g == 1) ? act : (g == 0) ? y1 : (g == 3) ? y2 : y3;
            float ff = (g == 2) ? act : (g == 3) ? y1 : (g == 0) ? y2 : y3;
            float oo = (g == 3) ? act : (g == 2) ? y1 : (g == 1) ? y2 : y3;
            c[rr] = fmaf(gg, ii, c[rr] * ff);
            const float hv = tanhf(c[rr]) * oo;
            if (g == 0)
                hnxt[(size_t)(r0 + row) * Hh + j] = hv;
        }

        rg_barrier(myBar);   // includes __syncthreads (protects part reuse) + agent fences
    }

    // ---------- classifier: out = h_T @ W_ph + b_p (h_T is in buffer 0) ----------
    if (Cg == 0) {
        const float* __restrict__ hT = hbuf;   // t=255 wrote buffer 0
        for (int idx = tid; idx < RGR * NCLS; idx += NTHR) {
            const int row = idx / NCLS;
            const int cc  = idx - row * NCLS;
            float a = b_p[cc];
            for (int k = 0; k < Hh; ++k)
                a = fmaf(hT[(size_t)(r0 + row) * Hh + k], W_ph[k * NCLS + cc], a);
            out[(size_t)(r0 + row) * NCLS + cc] = a;
        }
    }
}

extern "C" void kernel_launch(void* const* d_in, const int* in_sizes, int n_in,
                              void* d_out, int out_size, void* d_ws, size_t ws_size,
                              hipStream_t stream) {
    const float* x    = (const float*)d_in[0];
    const float* W_gx = (const float*)d_in[1];
    const float* W_gh = (const float*)d_in[2];
    const float* b_g  = (const float*)d_in[3];
    const float* W_ix = (const float*)d_in[4];
    const float* W_ih = (const float*)d_in[5];
    const float* b_i  = (const float*)d_in[6];
    const float* W_fx = (const float*)d_in[7];
    const float* W_fh = (const float*)d_in[8];
    const float* b_f  = (const float*)d_in[9];
    const float* W_ox = (const float*)d_in[10];
    const float* W_oh = (const float*)d_in[11];
    const float* b_o  = (const float*)d_in[12];
    const float* W_ph = (const float*)d_in[13];
    const float* b_p  = (const float*)d_in[14];
    float* out = (float*)d_out;

    float*    hbuf = (float*)d_ws;                              // 2 x 1024 x 256 fp32 = 2 MB
    unsigned* bar  = (unsigned*)((char*)d_ws + 2u * Bsz * Hh * sizeof(float));
    const size_t clear_bytes = 2u * Bsz * Hh * sizeof(float) + NRG * 16 * sizeof(unsigned);

    // zero h buffer 0 (h_0 = 0) and all barrier state -> deterministic every call
    hipMemsetAsync(d_ws, 0, clear_bytes, stream);

    lstm_rg<<<dim3(NRG * NCG), dim3(NTHR), 0, stream>>>(
        x, W_gx, W_gh, b_g, W_ix, W_ih, b_i, W_fx, W_fh, b_f,
        W_ox, W_oh, b_o, W_ph, b_p, out, hbuf, bar);
}

// Round 3
// 4481.984 us; speedup vs baseline: 12.1997x; 2.8085x over previous
//
#include <hip/hip_runtime.h>

// LSTM B=1024, T=256, H=256, fp32.
// Grid = 512 blocks = 32 rowgroups (32 rows) x 16 colgroups (16 hcols).
// Block = 256 thr = 4 waves (k-slices of 64); lane = gate(4) x hcol(16).
// Weights pinned in VGPRs (32 f32x2 per thread, v_pk_fma_f32 path).
// Cross-block h exchange via per-access coherent (agent-scope, sc0 sc1)
// atomic loads/stores -- NO acquire fences, NO L2 invalidation.
// Per step: cooperative h-tile stage to LDS -> phase A matvec partials ->
// phase B k-reduce + activations + c/h update -> per-rowgroup 16-block barrier.

#define Bsz   1024
#define Tt    256
#define Hh    256
#define NCLS  10
#define RGR   32
#define NRG   (Bsz / RGR)    // 32
#define NCG   16
#define NTHR  256
#define NW    4              // waves per block
#define KS    64             // k-slice per wave

typedef __attribute__((ext_vector_type(2))) float f32x2;
typedef unsigned long long u64;

__device__ __forceinline__ float sigmoid_f(float v) {
    const float e = expf(-fabsf(v));
    const float d = 1.0f + e;
    const float num = (v >= 0.0f) ? 1.0f : e;
    return num / d;
}

// coherent (agent-scope) accessors: per-access sc0/sc1, bypass stale L1/L2
__device__ __forceinline__ u64 coh_load64(const u64* p) {
    return __hip_atomic_load((u64*)p, __ATOMIC_RELAXED, __HIP_MEMORY_SCOPE_AGENT);
}
__device__ __forceinline__ void coh_storef(float* p, float v) {
    __hip_atomic_store(p, v, __ATOMIC_RELAXED, __HIP_MEMORY_SCOPE_AGENT);
}

// 16-block sense-reversing barrier; b[0]=arrive ctr, b[1]=generation.
// __syncthreads drains each wave's vmcnt (stores reach coherence point)
// before tid0 arrives. No acquire fence: shared data is read coherently.
__device__ __forceinline__ void rg_barrier(unsigned* b) {
    __syncthreads();
    if (threadIdx.x == 0) {
        unsigned gen = __hip_atomic_load(b + 1, __ATOMIC_RELAXED, __HIP_MEMORY_SCOPE_AGENT);
        unsigned pos = __hip_atomic_fetch_add(b, 1u, __ATOMIC_RELEASE, __HIP_MEMORY_SCOPE_AGENT);
        if (pos == 15u) {
            __hip_atomic_store(b, 0u, __ATOMIC_RELAXED, __HIP_MEMORY_SCOPE_AGENT);
            __hip_atomic_store(b + 1, gen + 1u, __ATOMIC_RELEASE, __HIP_MEMORY_SCOPE_AGENT);
        } else {
            while (__hip_atomic_load(b + 1, __ATOMIC_RELAXED, __HIP_MEMORY_SCOPE_AGENT) == gen)
                __builtin_amdgcn_s_sleep(1);
        }
    }
    __syncthreads();
}

extern "C" __global__ void __launch_bounds__(NTHR, 2)
lstm_rg(const float* __restrict__ x,
        const float* __restrict__ W_gx, const float* __restrict__ W_gh, const float* __restrict__ b_g,
        const float* __restrict__ W_ix, const float* __restrict__ W_ih, const float* __restrict__ b_i,
        const float* __restrict__ W_fx, const float* __restrict__ W_fh, const float* __restrict__ b_f,
        const float* __restrict__ W_ox, const float* __restrict__ W_oh, const float* __restrict__ b_o,
        const float* __restrict__ W_ph, const float* __restrict__ b_p,
        float* __restrict__ out, float* __restrict__ hbuf, unsigned* __restrict__ bar)
{
    __shared__ float htile[RGR][Hh];       // 32 KB staged h rows (this RG)
    __shared__ float part[NW][RGR][64];    // 32 KB k-slice partials

    const int tid  = threadIdx.x;
    const int lane = tid & 63;
    const int q    = tid >> 6;            // wave = k-slice [q*KS, q*KS+KS)
    const int g    = lane >> 4;           // gate 0:g 1:i 2:f 3:o
    const int hc   = lane & 15;
    const int R    = blockIdx.x & 31;     // rowgroup
    const int Cg   = blockIdx.x >> 5;     // colgroup
    const int r0   = R * RGR;
    const int j    = Cg * 16 + hc;        // global h-column

    // --- pin this thread's 64 recurrent weights as 32 f32x2 regs ---
    const float* __restrict__ Wh =
        (g == 0) ? W_gh : (g == 1) ? W_ih : (g == 2) ? W_fh : W_oh;
    const float* __restrict__ wsrc = Wh + (size_t)(q * KS) * Hh + j;
    f32x2 w2[KS / 2];
    #pragma unroll
    for (int p = 0; p < KS / 2; ++p) {
        f32x2 t2;
        t2.x = wsrc[(size_t)(2 * p) * Hh];
        t2.y = wsrc[(size_t)(2 * p + 1) * Hh];
        w2[p] = t2;
    }

    // reference's bias swap preserved: f-gate uses b_o, o-gate uses b_f
    const float wxv = ((g == 0) ? W_gx : (g == 1) ? W_ix : (g == 2) ? W_fx : W_ox)[j];
    const float bbv = ((g == 0) ? b_g  : (g == 1) ? b_i  : (g == 2) ? b_o  : b_f )[j];

    float c[RGR / NW];
    #pragma unroll
    for (int rr = 0; rr < RGR / NW; ++rr) c[rr] = 0.0f;

    unsigned* myBar = bar + (size_t)R * 16;
    u64* hsh = (u64*)&htile[0][0];        // 4096 u64 view of the LDS tile

    for (int t = 0; t < Tt; ++t) {
        const float* hcur = hbuf + ((t & 1) ? (size_t)(Bsz * Hh) : (size_t)0);
        float*       hnxt = hbuf + ((t & 1) ? (size_t)0 : (size_t)(Bsz * Hh));

        // x_t for the 8 rows this wave finishes (independent, issues early)
        float xts[RGR / NW];
        #pragma unroll
        for (int rr = 0; rr < RGR / NW; ++rr)
            xts[rr] = x[(size_t)(r0 + q * (RGR / NW) + rr) * Tt + t];

        // ---- stage h tile (32 KB) cooperatively: 16 coherent 8B loads/thread ----
        {
            const u64* hg = (const u64*)(hcur + (size_t)r0 * Hh);
            u64 v[16];
            #pragma unroll
            for (int i = 0; i < 16; ++i)
                v[i] = coh_load64(hg + tid + i * NTHR);   // coalesced, 16 in flight
            #pragma unroll
            for (int i = 0; i < 16; ++i)
                hsh[tid + i * NTHR] = v[i];
        }
        __syncthreads();

        // ---------- phase A: partial matvecs, all 32 rows, own k-slice ----------
        f32x2 acc[RGR];
        #pragma unroll
        for (int r = 0; r < RGR; ++r) { acc[r].x = 0.0f; acc[r].y = 0.0f; }

        #pragma unroll
        for (int r = 0; r < RGR; ++r) {
            const float4* hp4 = reinterpret_cast<const float4*>(&htile[r][q * KS]);
            #pragma unroll
            for (int p4 = 0; p4 < KS / 4; ++p4) {
                const float4 hv = hp4[p4];
                f32x2 a; a.x = hv.x; a.y = hv.y;
                f32x2 b; b.x = hv.z; b.y = hv.w;
                acc[r] = __builtin_elementwise_fma(a, w2[2 * p4],     acc[r]);
                acc[r] = __builtin_elementwise_fma(b, w2[2 * p4 + 1], acc[r]);
            }
        }

        #pragma unroll
        for (int r = 0; r < RGR; ++r)
            part[q][r][lane] = acc[r].x + acc[r].y;
        __syncthreads();

        // ---------- phase B: reduce k-slices, activate, update c/h ----------
        #pragma unroll
        for (int rr = 0; rr < RGR / NW; ++rr) {
            const int row = q * (RGR / NW) + rr;
            float s = part[0][row][lane] + part[1][row][lane]
                    + part[2][row][lane] + part[3][row][lane];
            float pre = s + fmaf(xts[rr], wxv, bbv);
            float act = (g == 0) ? tanhf(pre) : sigmoid_f(pre);
            float y1 = __shfl_xor(act, 16);
            float y2 = __shfl_xor(act, 32);
            float y3 = __shfl_xor(y1, 32);
            float gg = (g == 0) ? act : (g == 1) ? y1 : (g == 2) ? y2 : y3;
            float ii = (g == 1) ? act : (g == 0) ? y1 : (g == 3) ? y2 : y3;
            float ff = (g == 2) ? act : (g == 3) ? y1 : (g == 0) ? y2 : y3;
            float oo = (g == 3) ? act : (g == 2) ? y1 : (g == 1) ? y2 : y3;
            c[rr] = fmaf(gg, ii, c[rr] * ff);
            const float hv = tanhf(c[rr]) * oo;
            if (g == 0)
                coh_storef(&hnxt[(size_t)(r0 + row) * Hh + j], hv);
        }

        rg_barrier(myBar);
    }

    // ---------- classifier: out = h_T @ W_ph + b_p (h_T in buffer 0) ----------
    if (Cg == 0) {
        // stage h_T tile coherently into LDS (htile reusable here)
        const u64* hg = (const u64*)(hbuf + (size_t)r0 * Hh);
        #pragma unroll
        for (int i = 0; i < 16; ++i)
            hsh[tid + i * NTHR] = coh_load64(hg + tid + i * NTHR);
        __syncthreads();

        for (int idx = tid; idx < RGR * NCLS; idx += NTHR) {
            const int row = idx / NCLS;
            const int cc  = idx - row * NCLS;
            float a = b_p[cc];
            for (int k = 0; k < Hh; ++k)
                a = fmaf(htile[row][k], W_ph[k * NCLS + cc], a);
            out[(size_t)(r0 + row) * NCLS + cc] = a;
        }
    }
}

extern "C" void kernel_launch(void* const* d_in, const int* in_sizes, int n_in,
                              void* d_out, int out_size, void* d_ws, size_t ws_size,
                              hipStream_t stream) {
    const float* x    = (const float*)d_in[0];
    const float* W_gx = (const float*)d_in[1];
    const float* W_gh = (const float*)d_in[2];
    const float* b_g  = (const float*)d_in[3];
    const float* W_ix = (const float*)d_in[4];
    const float* W_ih = (const float*)d_in[5];
    const float* b_i  = (const float*)d_in[6];
    const float* W_fx = (const float*)d_in[7];
    const float* W_fh = (const float*)d_in[8];
    const float* b_f  = (const float*)d_in[9];
    const float* W_ox = (const float*)d_in[10];
    const float* W_oh = (const float*)d_in[11];
    const float* b_o  = (const float*)d_in[12];
    const float* W_ph = (const float*)d_in[13];
    const float* b_p  = (const float*)d_in[14];
    float* out = (float*)d_out;

    float*    hbuf = (float*)d_ws;   // 2 x 1 MB ping-pong
    unsigned* bar  = (unsigned*)((char*)d_ws + 2u * Bsz * Hh * sizeof(float));
    const size_t clear_bytes = 2u * Bsz * Hh * sizeof(float) + NRG * 16 * sizeof(unsigned);

    hipMemsetAsync(d_ws, 0, clear_bytes, stream);   // h0 = 0 + barrier state

    lstm_rg<<<dim3(NRG * NCG), dim3(NTHR), 0, stream>>>(
        x, W_gx, W_gh, b_g, W_ix, W_ih, b_i, W_fx, W_fh, b_f,
        W_ox, W_oh, b_o, W_ph, b_p, out, hbuf, bar);
}

// Round 4
// 2716.357 us; speedup vs baseline: 20.1295x; 1.6500x over previous
//
#include <hip/hip_runtime.h>

// LSTM B=1024, T=256, H=256, fp32. Whole-GPU persistent design v3.
// Grid = 256 blocks (1/CU) = 64 rowgroups (16 rows) x 4 colgroups (64 hcols x 4 gates).
// Block = 512 thr = 8 waves = 8 kappa-slices (K=32). Lane l owns all 4 gates of
// hcol (64*cg + l): weights = 4 gates x 32 k = 64 f32x2 VGPRs (v_pk_fma_f32).
// Phase A: full-wave-broadcast ds_read_b128 of the h-tile (LDS), 16 FMA per 16B read
// -> LDS delivery BW == VALU floor. Cross-wave k-reduction via padded part[] LDS.
// Own 64 hcols are written straight into the LDS h-tile (no global round-trip);
// the other 192 cols staged via per-access coherent (agent-scope) loads.
// Per-rowgroup barrier is only 4 blocks.

#define Bsz   1024
#define Tt    256
#define Hh    256
#define NCLS  10
#define RGR   16
#define NRG   64
#define NCG   4
#define NTHR  512

typedef __attribute__((ext_vector_type(2))) float f32x2;
typedef unsigned long long u64;

__device__ __forceinline__ float fast_sigmoid(float v) {
    const float e = __expf(-fabsf(v));           // in (0,1], never overflows
    const float p = __builtin_amdgcn_rcpf(1.0f + e);
    return (v >= 0.0f) ? p : 1.0f - p;
}
__device__ __forceinline__ float fast_tanh(float v) {
    const float e = __expf(-2.0f * fabsf(v));    // in (0,1]
    const float t = (1.0f - e) * __builtin_amdgcn_rcpf(1.0f + e);
    return copysignf(t, v);
}

// coherent (agent-scope) accessors: per-access sc0/sc1, no cache invalidation
__device__ __forceinline__ u64 coh_load64(const u64* p) {
    return __hip_atomic_load((u64*)p, __ATOMIC_RELAXED, __HIP_MEMORY_SCOPE_AGENT);
}
__device__ __forceinline__ void coh_storef(float* p, float v) {
    __hip_atomic_store(p, v, __ATOMIC_RELAXED, __HIP_MEMORY_SCOPE_AGENT);
}

// N-block sense-reversing barrier; b[0]=arrive ctr, b[1]=generation.
__device__ __forceinline__ void rg_barrier(unsigned* b, unsigned members) {
    __syncthreads();
    if (threadIdx.x == 0) {
        unsigned gen = __hip_atomic_load(b + 1, __ATOMIC_RELAXED, __HIP_MEMORY_SCOPE_AGENT);
        unsigned pos = __hip_atomic_fetch_add(b, 1u, __ATOMIC_RELEASE, __HIP_MEMORY_SCOPE_AGENT);
        if (pos == members - 1u) {
            __hip_atomic_store(b, 0u, __ATOMIC_RELAXED, __HIP_MEMORY_SCOPE_AGENT);
            __hip_atomic_store(b + 1, gen + 1u, __ATOMIC_RELEASE, __HIP_MEMORY_SCOPE_AGENT);
        } else {
            while (__hip_atomic_load(b + 1, __ATOMIC_RELAXED, __HIP_MEMORY_SCOPE_AGENT) == gen)
                __builtin_amdgcn_s_sleep(1);
        }
    }
    __syncthreads();
}

extern "C" __global__ void __launch_bounds__(NTHR, 2)
lstm_c4(const float* __restrict__ x,
        const float* __restrict__ W_gx, const float* __restrict__ W_gh, const float* __restrict__ b_g,
        const float* __restrict__ W_ix, const float* __restrict__ W_ih, const float* __restrict__ b_i,
        const float* __restrict__ W_fx, const float* __restrict__ W_fh, const float* __restrict__ b_f,
        const float* __restrict__ W_ox, const float* __restrict__ W_oh, const float* __restrict__ b_o,
        const float* __restrict__ W_ph, const float* __restrict__ b_p,
        float* __restrict__ out, float* __restrict__ hbuf, unsigned* __restrict__ bar)
{
    __shared__ float htile[RGR][Hh];        // 16 KB: h_t (global k layout)
    __shared__ float part[4 * 64 * 36];     // 36 KB: [rr][hc][w*4+g], stride 36 (16B-aligned)

    const int tid  = threadIdx.x;
    const int lane = tid & 63;
    const int wv   = tid >> 6;              // kappa-slice [32wv, 32wv+32)
    const int rg   = blockIdx.x & 63;       // rowgroup (4 blocks of rg share XCD: bid%8==rg%8)
    const int cg   = blockIdx.x >> 6;       // colgroup 0..3
    const int r0   = rg * RGR;
    const int j    = cg * 64 + lane;        // my hcol (global), also phase-B col for tid<256

    // ---- pin weights: all 4 gates of hcol j, k in [32wv, 32wv+32) -> 64 f32x2 ----
    const float* __restrict__ Wptr[4] = {W_gh, W_ih, W_fh, W_oh};
    f32x2 w2[4][16];
    #pragma unroll
    for (int g = 0; g < 4; ++g) {
        const float* __restrict__ src = Wptr[g] + (size_t)(32 * wv) * Hh + j;
        #pragma unroll
        for (int kk = 0; kk < 16; ++kk) {
            f32x2 t2;
            t2.x = src[(size_t)(2 * kk) * Hh];
            t2.y = src[(size_t)(2 * kk + 1) * Hh];
            w2[g][kk] = t2;
        }
    }

    // phase-B per-column constants (tid<256 threads own states (4*ch + sr, hc))
    // reference bias swap preserved: f-gate uses b_o, o-gate uses b_f.
    const int sr = tid >> 6;                // 0..3 (valid role for tid<256)
    const int hc = tid & 63;
    float wxv[4], bbv[4], c_st[4];
    wxv[0] = W_gx[j]; wxv[1] = W_ix[j]; wxv[2] = W_fx[j]; wxv[3] = W_ox[j];
    bbv[0] = b_g[j];  bbv[1] = b_i[j];  bbv[2] = b_o[j];  bbv[3] = b_f[j];
    #pragma unroll
    for (int ch = 0; ch < 4; ++ch) c_st[ch] = 0.0f;

    // staging role: thread stages row rs, k-octet ko (skips own colgroup's k-range)
    const int rs = tid >> 5;                // 0..15
    const int ko = tid & 31;                // octet: k0 = 8*ko
    const bool stage_active = ((ko >> 3) != cg);

    // init own-col region of htile to h_0 = 0 (staging never touches it)
    if (!stage_active) {
        #pragma unroll
        for (int i = 0; i < 8; ++i) htile[rs][8 * ko + i] = 0.0f;
    }

    unsigned* myBar = bar + (size_t)rg * 16;

    for (int t = 0; t < Tt; ++t) {
        const float* hcur = hbuf + ((t & 1) ? (size_t)(Bsz * Hh) : (size_t)0);
        float*       hnxt = hbuf + ((t & 1) ? (size_t)0 : (size_t)(Bsz * Hh));

        // x_t for the 4 states this thread finishes (L1-cached broadcast loads)
        float xv[4];
        #pragma unroll
        for (int ch = 0; ch < 4; ++ch)
            xv[ch] = x[(size_t)(r0 + 4 * ch + sr) * Tt + t];

        // ---- stage non-own 192 cols of h tile: 4 coherent u64 loads + LDS write ----
        if (stage_active) {
            const u64* src = (const u64*)(hcur + (size_t)(r0 + rs) * Hh + 8 * ko);
            u64 v0 = coh_load64(src + 0);
            u64 v1 = coh_load64(src + 1);
            u64 v2 = coh_load64(src + 2);
            u64 v3 = coh_load64(src + 3);
            u64* dst = (u64*)&htile[rs][8 * ko];
            dst[0] = v0; dst[1] = v1; dst[2] = v2; dst[3] = v3;
        }
        __syncthreads();

        // ---- 4 row-chunks: phase A (broadcast b128 + pk-fma), part, phase B ----
        #pragma unroll
        for (int ch = 0; ch < 4; ++ch) {
            f32x2 acc[4][4];
            #pragma unroll
            for (int rr = 0; rr < 4; ++rr)
                #pragma unroll
                for (int g = 0; g < 4; ++g) { acc[rr][g].x = 0.0f; acc[rr][g].y = 0.0f; }

            #pragma unroll
            for (int rr = 0; rr < 4; ++rr) {
                const float4* hq = reinterpret_cast<const float4*>(&htile[4 * ch + rr][32 * wv]);
                #pragma unroll
                for (int i = 0; i < 8; ++i) {
                    const float4 hv = hq[i];
                    f32x2 hA; hA.x = hv.x; hA.y = hv.y;
                    f32x2 hB; hB.x = hv.z; hB.y = hv.w;
                    #pragma unroll
                    for (int g = 0; g < 4; ++g) {
                        acc[rr][g] = __builtin_elementwise_fma(hA, w2[g][2 * i],     acc[rr][g]);
                        acc[rr][g] = __builtin_elementwise_fma(hB, w2[g][2 * i + 1], acc[rr][g]);
                    }
                }
            }

            // horizontal add + publish: part[rr][lane][wv*4 + g]
            #pragma unroll
            for (int rr = 0; rr < 4; ++rr) {
                float4 v;
                v.x = acc[rr][0].x + acc[rr][0].y;
                v.y = acc[rr][1].x + acc[rr][1].y;
                v.z = acc[rr][2].x + acc[rr][2].y;
                v.w = acc[rr][3].x + acc[rr][3].y;
                *reinterpret_cast<float4*>(&part[((rr << 6) + lane) * 36 + (wv << 2)]) = v;
            }
            __syncthreads();

            // phase B: tid<256 finishes state (row 4*ch+sr, hcol hc)
            if (tid < 256) {
                const float* pp = &part[((sr << 6) + hc) * 36];
                float sg = 0.0f, si = 0.0f, sf = 0.0f, so = 0.0f;
                #pragma unroll
                for (int w = 0; w < 8; ++w) {
                    const float4 v = *reinterpret_cast<const float4*>(pp + (w << 2));
                    sg += v.x; si += v.y; sf += v.z; so += v.w;
                }
                const float gg = fast_tanh   (sg + fmaf(xv[ch], wxv[0], bbv[0]));
                const float ii = fast_sigmoid(si + fmaf(xv[ch], wxv[1], bbv[1]));
                const float ff = fast_sigmoid(sf + fmaf(xv[ch], wxv[2], bbv[2]));
                const float oo = fast_sigmoid(so + fmaf(xv[ch], wxv[3], bbv[3]));
                c_st[ch] = fmaf(gg, ii, c_st[ch] * ff);
                const float hv = fast_tanh(c_st[ch]) * oo;
                const int row = 4 * ch + sr;
                coh_storef(&hnxt[(size_t)(r0 + row) * Hh + j], hv);  // for other 3 blocks
                htile[row][j & 255] = hv;                            // own col, next step's A
            }
            __syncthreads();
        }

        rg_barrier(myBar, NCG);
    }

    // ---- classifier: out = h_T @ W_ph + b_p  (h_T in buffer 0; cg==0 blocks) ----
    if (cg == 0) {
        for (int idx = tid; idx < RGR * NCLS; idx += NTHR) {
            const int row = idx / NCLS;
            const int cc  = idx - row * NCLS;
            float a = b_p[cc];
            const u64* hrow = (const u64*)(hbuf + (size_t)(r0 + row) * Hh);
            for (int k2 = 0; k2 < Hh / 2; ++k2) {
                u64 pv = coh_load64(hrow + k2);
                float2 hf = *reinterpret_cast<float2*>(&pv);
                a = fmaf(hf.x, W_ph[(2 * k2) * NCLS + cc], a);
                a = fmaf(hf.y, W_ph[(2 * k2 + 1) * NCLS + cc], a);
            }
            out[(size_t)(r0 + row) * NCLS + cc] = a;
        }
    }
}

extern "C" void kernel_launch(void* const* d_in, const int* in_sizes, int n_in,
                              void* d_out, int out_size, void* d_ws, size_t ws_size,
                              hipStream_t stream) {
    const float* x    = (const float*)d_in[0];
    const float* W_gx = (const float*)d_in[1];
    const float* W_gh = (const float*)d_in[2];
    const float* b_g  = (const float*)d_in[3];
    const float* W_ix = (const float*)d_in[4];
    const float* W_ih = (const float*)d_in[5];
    const float* b_i  = (const float*)d_in[6];
    const float* W_fx = (const float*)d_in[7];
    const float* W_fh = (const float*)d_in[8];
    const float* b_f  = (const float*)d_in[9];
    const float* W_ox = (const float*)d_in[10];
    const float* W_oh = (const float*)d_in[11];
    const float* b_o  = (const float*)d_in[12];
    const float* W_ph = (const float*)d_in[13];
    const float* b_p  = (const float*)d_in[14];
    float* out = (float*)d_out;

    float*    hbuf = (float*)d_ws;   // 2 x 1 MB ping-pong
    unsigned* bar  = (unsigned*)((char*)d_ws + 2u * Bsz * Hh * sizeof(float));
    const size_t clear_bytes = 2u * Bsz * Hh * sizeof(float) + NRG * 16 * sizeof(unsigned);

    hipMemsetAsync(d_ws, 0, clear_bytes, stream);   // h0 = 0 + barrier state

    lstm_c4<<<dim3(NRG * NCG), dim3(NTHR), 0, stream>>>(
        x, W_gx, W_gh, b_g, W_ix, W_ih, b_i, W_fx, W_fh, b_f,
        W_ox, W_oh, b_o, W_ph, b_p, out, hbuf, bar);
}

// Round 5
// 2517.891 us; speedup vs baseline: 21.7162x; 1.0788x over previous
//
#include <hip/hip_runtime.h>

// LSTM B=1024, T=256, H=256, fp32. Whole-GPU persistent design v4.
// Grid = 256 blocks = 64 rowgroups (16 rows) x 4 colgroups (64 hcols x 4 gates).
// Block = 512 thr = 8 waves = 8 k-slices (K=32). Lane owns all 4 gates of one
// hcol; weights = 64 f32x2 VGPRs, pinned via asm opaque (round-4 counters showed
// VGPR=104 -> compiler was re-loading weights from L2 every step).
// Changes vs v3:
//  - per-wave self-staging: wave wv stages only h cols [32wv,32wv+32) (its own
//    phase-A input); waves whose slice is block-local skip global exchange.
//  - 4-block barrier replaced by per-block flag fcnt[rg][cg] = steps published;
//    staging waves spin on exactly one partner flag. Ping-pong safety: a block's
//    B(t) stores happen after its waves waited fcnt>=t, which happens after
//    partners' post-B sync of t-1, which is after partners consumed h(t-1).
//  - h exchange stays per-access coherent (agent scope) -> no cache invalidates.

#define Bsz   1024
#define Tt    256
#define Hh    256
#define NCLS  10
#define RGR   16
#define NRG   64
#define NCG   4
#define NTHR  512
#define HSZ   ((size_t)Bsz * Hh)

typedef __attribute__((ext_vector_type(2))) float f32x2;
typedef unsigned long long u64;

__device__ __forceinline__ float fast_sigmoid(float v) {
    const float e = __expf(-fabsf(v));
    const float p = __builtin_amdgcn_rcpf(1.0f + e);
    return (v >= 0.0f) ? p : 1.0f - p;
}
__device__ __forceinline__ float fast_tanh(float v) {
    const float e = __expf(-2.0f * fabsf(v));
    const float t = (1.0f - e) * __builtin_amdgcn_rcpf(1.0f + e);
    return copysignf(t, v);
}

__device__ __forceinline__ u64 coh_load64(const u64* p) {
    return __hip_atomic_load((u64*)p, __ATOMIC_RELAXED, __HIP_MEMORY_SCOPE_AGENT);
}
__device__ __forceinline__ unsigned coh_load32(const unsigned* p) {
    return __hip_atomic_load((unsigned*)p, __ATOMIC_RELAXED, __HIP_MEMORY_SCOPE_AGENT);
}
__device__ __forceinline__ void coh_storef(float* p, float v) {
    __hip_atomic_store(p, v, __ATOMIC_RELAXED, __HIP_MEMORY_SCOPE_AGENT);
}

extern "C" __global__ void __launch_bounds__(NTHR, 2)
lstm_v4(const float* __restrict__ x,
        const float* __restrict__ W_gx, const float* __restrict__ W_gh, const float* __restrict__ b_g,
        const float* __restrict__ W_ix, const float* __restrict__ W_ih, const float* __restrict__ b_i,
        const float* __restrict__ W_fx, const float* __restrict__ W_fh, const float* __restrict__ b_f,
        const float* __restrict__ W_ox, const float* __restrict__ W_oh, const float* __restrict__ b_o,
        const float* __restrict__ W_ph, const float* __restrict__ b_p,
        float* __restrict__ out, float* __restrict__ hbuf, unsigned* __restrict__ fcnt)
{
    __shared__ float htile[RGR][Hh];        // 16 KB, col-partitioned per wave
    __shared__ float part[4 * 64 * 36];     // 36 KB, [row][hc][w*4+g] stride 36

    const int tid  = threadIdx.x;
    const int lane = tid & 63;
    const int wv   = tid >> 6;              // k-slice [32wv, 32wv+32)
    const int rg   = blockIdx.x & 63;
    const int cg   = blockIdx.x >> 6;
    const int r0   = rg * RGR;
    const int j    = cg * 64 + lane;        // my hcol (global)
    const int scg  = wv >> 1;               // colgroup that produces my k-slice
    const bool local_slice = (scg == cg);

    // ---- pin weights: 4 gates x k-slice of 32 for hcol j -> 64 f32x2 ----
    const float* __restrict__ Wptr[4] = {W_gh, W_ih, W_fh, W_oh};
    f32x2 w2[4][16];
    #pragma unroll
    for (int g = 0; g < 4; ++g) {
        const float* __restrict__ src = Wptr[g] + (size_t)(32 * wv) * Hh + j;
        #pragma unroll
        for (int kk = 0; kk < 16; ++kk) {
            f32x2 t2;
            t2.x = src[(size_t)(2 * kk) * Hh];
            t2.y = src[(size_t)(2 * kk + 1) * Hh];
            w2[g][kk] = t2;
        }
    }
    // force register residency (round 4: compiler re-loaded these every step)
    #pragma unroll
    for (int g = 0; g < 4; ++g)
        #pragma unroll
        for (int kk = 0; kk < 16; ++kk)
            asm volatile("" : "+v"(w2[g][kk]));

    // phase-B constants; reference bias swap preserved (f uses b_o, o uses b_f)
    float wxv[4], bbv[4], c_st[4];
    wxv[0] = W_gx[j]; wxv[1] = W_ix[j]; wxv[2] = W_fx[j]; wxv[3] = W_ox[j];
    bbv[0] = b_g[j];  bbv[1] = b_i[j];  bbv[2] = b_o[j];  bbv[3] = b_f[j];
    #pragma unroll
    for (int ch = 0; ch < 4; ++ch) c_st[ch] = 0.0f;

    unsigned* fbase = fcnt + rg * NCG;

    // htile = h_0 = 0 (local-slice waves read it at t=0)
    for (int i = tid; i < RGR * Hh; i += NTHR) (&htile[0][0])[i] = 0.0f;
    __syncthreads();

    for (int t = 0; t < Tt; ++t) {
        const float* hcur = hbuf + ((t & 1) ? HSZ : 0);
        float*       hnxt = hbuf + ((t & 1) ? 0 : HSZ);

        // x_t for the 4 rows this (B-)wave finishes; wave-uniform broadcast loads
        float xv[4];
        if (wv < 4) {
            #pragma unroll
            for (int ch = 0; ch < 4; ++ch)
                xv[ch] = x[(size_t)(r0 + 4 * ch + wv) * Tt + t];
        }

        // ---- per-wave self-staging of my 32-col slice (16 rows x 128 B) ----
        if (!local_slice) {
            if (t > 0) {
                const unsigned* fp = fbase + scg;
                while (coh_load32(fp) < (unsigned)t) __builtin_amdgcn_s_sleep(1);
            }
            u64 vals[4];
            #pragma unroll
            for (int i = 0; i < 4; ++i) {
                const int idx = lane + 64 * i;          // 256 u64 slots
                const int row = idx >> 4, cu = idx & 15;
                vals[i] = coh_load64((const u64*)hcur +
                                     (size_t)(r0 + row) * (Hh / 2) + 16 * wv + cu);
            }
            #pragma unroll
            for (int i = 0; i < 4; ++i) {
                const int idx = lane + 64 * i;
                const int row = idx >> 4, cu = idx & 15;
                *(u64*)&htile[row][32 * wv + 2 * cu] = vals[i];
            }
        }
        // no block sync: each wave's phase A reads only the slice it just wrote
        // (own ds ordering), or cols written before the previous step's sync.

        // ---- 4 row-chunks: phase A -> part -> sync -> phase B -> sync ----
        #pragma unroll
        for (int ch = 0; ch < 4; ++ch) {
            f32x2 acc[4][4];
            #pragma unroll
            for (int rr = 0; rr < 4; ++rr)
                #pragma unroll
                for (int g = 0; g < 4; ++g) { acc[rr][g].x = 0.0f; acc[rr][g].y = 0.0f; }

            #pragma unroll
            for (int rr = 0; rr < 4; ++rr) {
                const float4* hq = reinterpret_cast<const float4*>(&htile[4 * ch + rr][32 * wv]);
                #pragma unroll
                for (int i = 0; i < 8; ++i) {
                    const float4 hv = hq[i];
                    f32x2 hA; hA.x = hv.x; hA.y = hv.y;
                    f32x2 hB; hB.x = hv.z; hB.y = hv.w;
                    #pragma unroll
                    for (int g = 0; g < 4; ++g) {
                        acc[rr][g] = __builtin_elementwise_fma(hA, w2[g][2 * i],     acc[rr][g]);
                        acc[rr][g] = __builtin_elementwise_fma(hB, w2[g][2 * i + 1], acc[rr][g]);
                    }
                }
            }

            #pragma unroll
            for (int rr = 0; rr < 4; ++rr) {
                float4 v;
                v.x = acc[rr][0].x + acc[rr][0].y;
                v.y = acc[rr][1].x + acc[rr][1].y;
                v.z = acc[rr][2].x + acc[rr][2].y;
                v.w = acc[rr][3].x + acc[rr][3].y;
                *reinterpret_cast<float4*>(&part[((rr << 6) + lane) * 36 + (wv << 2)]) = v;
            }
            __syncthreads();

            if (tid < 256) {                 // waves 0..3: finish (row 4ch+wv, hcol lane)
                const float* pp = &part[((wv << 6) + lane) * 36];
                float sg = 0.0f, si = 0.0f, sf = 0.0f, so = 0.0f;
                #pragma unroll
                for (int w = 0; w < 8; ++w) {
                    const float4 v = *reinterpret_cast<const float4*>(pp + (w << 2));
                    sg += v.x; si += v.y; sf += v.z; so += v.w;
                }
                const float gg = fast_tanh   (sg + fmaf(xv[ch], wxv[0], bbv[0]));
                const float ii = fast_sigmoid(si + fmaf(xv[ch], wxv[1], bbv[1]));
                const float ff = fast_sigmoid(sf + fmaf(xv[ch], wxv[2], bbv[2]));
                const float oo = fast_sigmoid(so + fmaf(xv[ch], wxv[3], bbv[3]));
                c_st[ch] = fmaf(gg, ii, c_st[ch] * ff);
                const float hv = fast_tanh(c_st[ch]) * oo;
                const int row = 4 * ch + wv;
                coh_storef(&hnxt[(size_t)(r0 + row) * Hh + j], hv);
                htile[row][j] = hv;          // own cols, read by local-slice waves
            }
            __syncthreads();                 // part[] reuse + htile visibility
        }

        // all B stores vmcnt-drained at the barrier above -> publish h(t+1)
        if (tid == 0)
            __hip_atomic_store(fbase + cg, (unsigned)(t + 1),
                               __ATOMIC_RELEASE, __HIP_MEMORY_SCOPE_AGENT);
    }

    // ---- classifier: out = h_T @ W_ph + b_p (h_T in buffer 0; cg==0 blocks) ----
    if (cg == 0) {
        for (int c = 1; c < NCG; ++c)
            while (coh_load32(fbase + c) < (unsigned)Tt) __builtin_amdgcn_s_sleep(1);
        for (int idx = tid; idx < RGR * NCLS; idx += NTHR) {
            const int row = idx / NCLS;
            const int cc  = idx - row * NCLS;
            float a = b_p[cc];
            const u64* hrow = (const u64*)(hbuf + (size_t)(r0 + row) * Hh);
            for (int k2 = 0; k2 < Hh / 2; ++k2) {
                u64 pv = coh_load64(hrow + k2);
                float2 hf = *reinterpret_cast<float2*>(&pv);
                a = fmaf(hf.x, W_ph[(2 * k2) * NCLS + cc], a);
                a = fmaf(hf.y, W_ph[(2 * k2 + 1) * NCLS + cc], a);
            }
            out[(size_t)(r0 + row) * NCLS + cc] = a;
        }
    }
}

extern "C" void kernel_launch(void* const* d_in, const int* in_sizes, int n_in,
                              void* d_out, int out_size, void* d_ws, size_t ws_size,
                              hipStream_t stream) {
    const float* x    = (const float*)d_in[0];
    const float* W_gx = (const float*)d_in[1];
    const float* W_gh = (const float*)d_in[2];
    const float* b_g  = (const float*)d_in[3];
    const float* W_ix = (const float*)d_in[4];
    const float* W_ih = (const float*)d_in[5];
    const float* b_i  = (const float*)d_in[6];
    const float* W_fx = (const float*)d_in[7];
    const float* W_fh = (const float*)d_in[8];
    const float* b_f  = (const float*)d_in[9];
    const float* W_ox = (const float*)d_in[10];
    const float* W_oh = (const float*)d_in[11];
    const float* b_o  = (const float*)d_in[12];
    const float* W_ph = (const float*)d_in[13];
    const float* b_p  = (const float*)d_in[14];
    float* out = (float*)d_out;

    float*    hbuf = (float*)d_ws;                       // 2 MB ping-pong
    unsigned* fcnt = (unsigned*)((char*)d_ws + 2 * HSZ * sizeof(float));
    const size_t clear_bytes = 2 * HSZ * sizeof(float) + NRG * NCG * sizeof(unsigned);

    hipMemsetAsync(d_ws, 0, clear_bytes, stream);        // h0 = 0 + flags = 0

    lstm_v4<<<dim3(NRG * NCG), dim3(NTHR), 0, stream>>>(
        x, W_gx, W_gh, b_g, W_ix, W_ih, b_i, W_fx, W_fh, b_f,
        W_ox, W_oh, b_o, W_ph, b_p, out, hbuf, fcnt);
}